// Round 1
// 171.249 us; speedup vs baseline: 1.1131x; 1.1131x over previous
//
#include <hip/hip_runtime.h>

#define B_    32
#define CIN_  128
#define H_    64
#define W_    64
#define COUT_ 128
#define NK_   4
#define HID_  32
#define TEMP_ 34.0f

typedef short bf16x8 __attribute__((ext_vector_type(8)));
typedef float f32x16 __attribute__((ext_vector_type(16)));

__device__ __forceinline__ short f2bf(float f) {
    union { float f; unsigned u; } c; c.f = f;
    unsigned r = (c.u + 0x7FFFu + ((c.u >> 16) & 1u)) >> 16;
    return (short)r;
}

// =========== k_context: ctx[b][ci] = mean over HxW (one wave per (b,ci)) =====
// Replaces k_prep's atomic partial sums: plain coalesced float4 reduction.
__global__ __launch_bounds__(64) void k_context(const float* __restrict__ x,
                                                float* __restrict__ ctx) {
    const int bc = blockIdx.x;
    const float* p = x + (size_t)bc * (H_ * W_);
    const int lane = threadIdx.x;
    float s = 0.f;
    for (int i = lane * 4; i < H_ * W_; i += 64 * 4) {
        float4 v = *(const float4*)(p + i);
        s += v.x + v.y + v.z + v.w;
    }
    for (int off = 32; off > 0; off >>= 1) s += __shfl_down(s, off, 64);
    if (lane == 0) ctx[bc] = s * (1.0f / (H_ * W_));
}

// =========== k_aggw: fused attention + weight aggregation + agg bias =========
// Every block redundantly computes att for its b (tiny: 128x32 + 32x4 MACs),
// removing the serial single-block k_att dispatch.
__global__ __launch_bounds__(256) void k_aggw(const float* __restrict__ ctx,
        const float* __restrict__ fc1w, const float* __restrict__ fc2w,
        const float* __restrict__ fc2b, const float* __restrict__ bias,
        const float* __restrict__ weight, short* __restrict__ aggwt,
        float* __restrict__ aggb) {
    __shared__ float hidp[8][32];
    __shared__ float shid[32];
    __shared__ float satt[NK_];
    const int tid = threadIdx.x;
    const int blk = blockIdx.x;
    const int b = blk >> 6;                 // 64 blocks per sample
    // hid partials: thread (part, hh) covers 16 ci
    {
        const int hh = tid & 31, part = tid >> 5;
        const float* c  = ctx + b * CIN_ + part * 16;
        const float* f1 = fc1w + hh * CIN_ + part * 16;
        float s = 0.f;
#pragma unroll
        for (int j = 0; j < 16; ++j) s += c[j] * f1[j];
        hidp[part][hh] = s;
    }
    __syncthreads();
    if (tid < 32) {
        float s = 0.f;
#pragma unroll
        for (int p = 0; p < 8; ++p) s += hidp[p][tid];
        shid[tid] = fmaxf(s, 0.f);
    }
    __syncthreads();
    if (tid == 0) {
        float lg[NK_]; float mx = -1e30f;
#pragma unroll
        for (int k = 0; k < NK_; ++k) {
            float s = fc2b[k];
            for (int hh = 0; hh < HID_; ++hh) s += shid[hh] * fc2w[k * HID_ + hh];
            lg[k] = s / TEMP_; mx = fmaxf(mx, lg[k]);
        }
        float den = 0.f;
#pragma unroll
        for (int k = 0; k < NK_; ++k) { lg[k] = expf(lg[k] - mx); den += lg[k]; }
        const float rd = 1.0f / den;
#pragma unroll
        for (int k = 0; k < NK_; ++k) satt[k] = lg[k] * rd;
    }
    __syncthreads();
    const float a0 = satt[0], a1 = satt[1], a2 = satt[2], a3 = satt[3];

    const int idx = blk * 256 + tid;
    const int ci = idx & 127;
    const int co = (idx >> 7) & 127;
    // aggregated bias: one thread per co (block owns 2 co's)
    if ((tid & 127) == 0)
        aggb[b * COUT_ + co] = a0 * bias[co] + a1 * bias[COUT_ + co]
                             + a2 * bias[2 * COUT_ + co] + a3 * bias[3 * COUT_ + co];

    const float* w0 = weight + ((size_t)co * CIN_ + ci) * 9;
    const float* w1 = w0 + (size_t)COUT_ * CIN_ * 9;
    const float* w2 = w1 + (size_t)COUT_ * CIN_ * 9;
    const float* w3 = w2 + (size_t)COUT_ * CIN_ * 9;
    short* o = aggwt + ((size_t)(b * COUT_ + co) * 9) * CIN_ + ci;
#pragma unroll
    for (int r = 0; r < 9; ++r)
        o[r * CIN_] = f2bf(a0 * w0[r] + a1 * w1[r] + a2 * w2[r] + a3 * w3[r]);
}

// =========== k_conv: 4-row blocks, B-register-reuse, A-in-regs ===========
// Block = (b, 4 h-rows). LDS: 6 input rows x 66 slots x 8 chunks(16B) = 50688 B.
// Swizzle: data (w, ci8') at chunk p = (ci8' + w) & 7 of slot w+1.
// Staging now reads f32 x directly (no xb pass): per wave-task (row, g):
// 8 coalesced 256B loads (one per ci), pack bf16x8, one swizzled ds_write_b128.
// Write chunk p = (g + w) & 7 of slot w+1  <=>  read ci8' = (p - w) & 7. Same
// bank balance as the read side (4*((g+w)&7) groups, 8 accesses/bank).
#define RBY 8448            // bytes per LDS row (66 slots * 128 B)
#define RSH 4224            // shorts per LDS row
__global__ __launch_bounds__(256, 2) void k_conv(const float* __restrict__ x,
        const short* __restrict__ aggwt, const float* __restrict__ aggb,
        float* __restrict__ out) {
    __shared__ short xt[6 * RSH];
    const int tid = threadIdx.x;
    const int blk = blockIdx.x;
    const int b = blk & 31;                 // all 16 blocks of b on XCD b&7
    const int h0 = (blk >> 5) * 4;
    const int lane = tid & 63;
    const int wv = tid >> 6;
    const int l31 = lane & 31;
    const int lane5 = lane >> 5;

    // zero halo slots (slot 0 and slot 65 of each of 6 rows) - written once
    if (tid < 96) {
        const int row = tid >> 4;
        const int q = tid & 15;
        const int cl = (q < 8) ? q : (512 + q);
        *(int4*)(&xt[row * RSH + cl * 8]) = make_int4(0, 0, 0, 0);
    }

    f32x16 acc[8];
#pragma unroll
    for (int t = 0; t < 8; ++t)
#pragma unroll
        for (int k = 0; k < 16; ++k) acc[t][k] = 0.f;

    const short* Ap = aggwt + (size_t)(b * COUT_ + wv * 32 + l31) * 9 * CIN_ + lane5 * 8;

    for (int half = 0; half < 2; ++half) {
        const int cib = half * 64;
        // stage 6 rows (ci-half): 48 wave-tasks (row 0..5, g 0..7), 12/wave
#pragma unroll
        for (int k = 0; k < 12; ++k) {
            const int task = k * 4 + wv;          // wave-uniform
            const int row = task >> 3;
            const int g = task & 7;
            const int in_h = h0 - 1 + row;
            bf16x8 v = (bf16x8){0, 0, 0, 0, 0, 0, 0, 0};
            if (in_h >= 0 && in_h < H_) {
                const float* gp = x + (((size_t)b * CIN_ + cib + g * 8) * H_ + in_h) * W_ + lane;
                float f[8];
#pragma unroll
                for (int j = 0; j < 8; ++j) f[j] = gp[j * (H_ * W_)];
#pragma unroll
                for (int j = 0; j < 8; ++j) v[j] = f2bf(f[j]);
            }
            *(bf16x8*)(&xt[row * RSH + ((lane + 1) * 8 + ((g + lane) & 7)) * 8]) = v;
        }
        __syncthreads();

#pragma unroll
        for (int kcl = 0; kcl < 4; ++kcl) {
            const int kc = half * 4 + kcl;
            bf16x8 av[9];
#pragma unroll
            for (int r = 0; r < 9; ++r)
                av[r] = *(const bf16x8*)(Ap + kc * 16 + r * CIN_);
#pragma unroll
            for (int ir = 0; ir < 6; ++ir) {
                bf16x8 bv[2][3];
#pragma unroll
                for (int i = 0; i < 2; ++i)
#pragma unroll
                    for (int kw = 0; kw < 3; ++kw) {
                        const int s = i * 32 + l31 + kw;
                        const int off = 16 * ((2 * kcl + lane5 + s - 1) & 7);
                        bv[i][kw] = *(const bf16x8*)((const char*)xt + ir * RBY + s * 128 + off);
                    }
#pragma unroll
                for (int orr = 0; orr < 4; ++orr) {
                    if (orr <= ir && ir <= orr + 2) {
                        const int kh = ir - orr;
#pragma unroll
                        for (int i = 0; i < 2; ++i)
#pragma unroll
                            for (int kw = 0; kw < 3; ++kw)
                                acc[orr * 2 + i] = __builtin_amdgcn_mfma_f32_32x32x16_bf16(
                                    av[kh * 3 + kw], bv[i][kw], acc[orr * 2 + i], 0, 0, 0);
                    }
                }
            }
        }
        if (half == 0) __syncthreads();     // drain readers before restaging
    }

    const float* ab = aggb + b * COUT_;
#pragma unroll
    for (int orr = 0; orr < 4; ++orr) {
#pragma unroll
        for (int i = 0; i < 2; ++i) {
            const int hh = h0 + orr;
            const int w = i * 32 + l31;
            float* op = out + ((size_t)b * COUT_ * H_ + hh) * W_ + w;
            const f32x16 a = acc[orr * 2 + i];
#pragma unroll
            for (int reg = 0; reg < 16; ++reg) {
                const int co = wv * 32 + (reg & 3) + 8 * (reg >> 2) + 4 * lane5;
                op[(size_t)co * (H_ * W_)] = a[reg] + ab[co];
            }
        }
    }
}

extern "C" void kernel_launch(void* const* d_in, const int* in_sizes, int n_in,
                              void* d_out, int out_size, void* d_ws, size_t ws_size,
                              hipStream_t stream) {
    const float* x    = (const float*)d_in[0];
    const float* fc1w = (const float*)d_in[1];
    const float* fc2w = (const float*)d_in[2];
    const float* fc2b = (const float*)d_in[3];
    const float* wgt  = (const float*)d_in[4];
    const float* bias = (const float*)d_in[5];
    float* out = (float*)d_out;

    char* ws = (char*)d_ws;
    float* ctx   = (float*)(ws + 0);            // 16 KB
    float* aggb  = (float*)(ws + 16384);        // 16 KB
    short* aggwt = (short*)(ws + 65536);        // 9,437,184 B
    // NEED = 9,502,720 B (same floor as the previous fallback path; the
    // harness provided >= 43 MB for the prior main path)

    k_context<<<dim3(B_ * CIN_), dim3(64), 0, stream>>>(x, ctx);
    k_aggw<<<dim3((B_ * COUT_ * CIN_) / 256), dim3(256), 0, stream>>>(
        ctx, fc1w, fc2w, fc2b, bias, wgt, aggwt, aggb);
    k_conv<<<dim3(B_ * (H_ / 4)), dim3(256), 0, stream>>>(x, aggwt, aggb, out);
}